// Round 8
// baseline (1572.453 us; speedup 1.0000x reference)
//
#include <hip/hip_runtime.h>

#define H 2048
#define I_DIM 4096
#define E_NUM 8
#define T_TOK 8192
#define SLOTS 16384
#define NTS2 72   // max 256-row tiles: sum_e ceil(Te/256) <= 64 + 7 = 71 (pad 72)

typedef __attribute__((ext_vector_type(8))) short bf16x8;
typedef __attribute__((ext_vector_type(4))) float f32x4;
typedef __attribute__((ext_vector_type(8))) unsigned short u16x8;

__device__ __forceinline__ unsigned short f2bf(float f) {
  union { float f; unsigned int u; } v; v.f = f;
  unsigned int r = v.u + 0x7fffu + ((v.u >> 16) & 1u);
  return (unsigned short)(r >> 16);
}

// async global->LDS, 16B per lane; LDS dest is wave-uniform base + lane*16
__device__ __forceinline__ void gload16(const unsigned short* g, unsigned short* l) {
  __builtin_amdgcn_global_load_lds(
      (const __attribute__((address_space(1))) unsigned int*)g,
      (__attribute__((address_space(3))) unsigned int*)l, 16, 0, 0);
}

// ---------------- x convert (f32 -> bf16) ----------------
__global__ __launch_bounds__(256) void k_cvt(const float* __restrict__ x,
                                             unsigned short* __restrict__ xb) {
  size_t i = ((size_t)blockIdx.x * 256 + threadIdx.x) * 8;
  f32x4 a = *(const f32x4*)(x + i);
  f32x4 b = *(const f32x4*)(x + i + 4);
  u16x8 o;
#pragma unroll
  for (int j = 0; j < 4; ++j) { o[j] = f2bf(a[j]); o[4 + j] = f2bf(b[j]); }
  *(u16x8*)(xb + i) = o;
}

// ---------------- weights: gate/up -> interleaved W2 (16-row groups), down -> dwb ----------------
// W2[e][b*32 + s] = gate[e][b*16+s] (s<16) | up[e][b*16+s-16] (s>=16)
__global__ __launch_bounds__(256) void k_cvt_w(
    const float* __restrict__ gw, const float* __restrict__ uw, const float* __restrict__ dw,
    unsigned short* __restrict__ w2b, unsigned short* __restrict__ dwb) {
  const size_t per = (size_t)E_NUM * I_DIM * H / 8;
  size_t gid = (size_t)blockIdx.x * 256 + threadIdx.x;
  const float* s; int which; size_t idx;
  if (gid < per)          { s = gw; which = 0; idx = gid; }
  else if (gid < 2 * per) { s = uw; which = 1; idx = gid - per; }
  else                    { s = dw; which = 2; idx = gid - 2 * per; }
  size_t i = idx * 8;
  f32x4 a = *(const f32x4*)(s + i);
  f32x4 b = *(const f32x4*)(s + i + 4);
  u16x8 o;
#pragma unroll
  for (int j = 0; j < 4; ++j) { o[j] = f2bf(a[j]); o[4 + j] = f2bf(b[j]); }
  if (which == 2) {
    *(u16x8*)(dwb + i) = o;
  } else {
    size_t row = i / H; size_t col = i % H;
    size_t e = row / I_DIM; int ii = (int)(row % I_DIM);
    size_t w2r = (size_t)e * (2 * I_DIM) + (size_t)((ii >> 4) * 32 + (ii & 15) + which * 16);
    *(u16x8*)(w2b + w2r * H + col) = o;
  }
}

// ---------------- router ----------------
__global__ __launch_bounds__(256) void k_router(
    const float* __restrict__ x, const float* __restrict__ rw,
    int* __restrict__ tok_e, float* __restrict__ tok_w,
    int* __restrict__ counts, float* __restrict__ probs_sum, float* __restrict__ z_sum) {
  __shared__ __align__(16) float s_rw[E_NUM * H];
  __shared__ float s_probs[E_NUM];
  __shared__ float s_z;
  __shared__ int s_cnt[E_NUM];
  int tid = threadIdx.x;
  if (tid < E_NUM) { s_probs[tid] = 0.f; s_cnt[tid] = 0; }
  if (tid == 0) s_z = 0.f;
  for (int i = tid * 4; i < E_NUM * H; i += 256 * 4)
    *(f32x4*)&s_rw[i] = *(const f32x4*)&rw[i];
  __syncthreads();

  int lane = tid & 63, wv = tid >> 6;

  for (int it = 0; it < 8; ++it) {
    int t = blockIdx.x * 32 + wv * 8 + it;
    const float* xr = x + (size_t)t * H;

    float acc[E_NUM];
#pragma unroll
    for (int e = 0; e < E_NUM; ++e) acc[e] = 0.f;
    for (int j = 0; j < H / 64; ++j) {
      int c = j * 64 + lane;
      float xv = xr[c];
#pragma unroll
      for (int e = 0; e < E_NUM; ++e) acc[e] = fmaf(xv, s_rw[e * H + c], acc[e]);
    }
#pragma unroll
    for (int e = 0; e < E_NUM; ++e) {
      float v = acc[e];
#pragma unroll
      for (int off = 32; off > 0; off >>= 1) v += __shfl_down(v, off, 64);
      acc[e] = v;
    }
    if (lane == 0) {
      int i0 = 0; float l0 = acc[0];
#pragma unroll
      for (int e = 1; e < E_NUM; ++e) if (acc[e] > l0) { l0 = acc[e]; i0 = e; }
      int i1 = -1; float l1 = -3.4e38f;
#pragma unroll
      for (int e = 0; e < E_NUM; ++e) if (e != i0 && acc[e] > l1) { l1 = acc[e]; i1 = e; }
      float w0 = 1.f / (1.f + expf(l1 - l0));
      tok_e[t * 2] = i0; tok_e[t * 2 + 1] = i1;
      tok_w[t * 2] = w0; tok_w[t * 2 + 1] = 1.f - w0;

      float s = 0.f; float p[E_NUM];
#pragma unroll
      for (int e = 0; e < E_NUM; ++e) { p[e] = expf(acc[e] - l0); s += p[e]; }
      float inv = 1.f / s;
#pragma unroll
      for (int e = 0; e < E_NUM; ++e) atomicAdd(&s_probs[e], p[e] * inv);
      atomicAdd(&s_z, l0 + logf(s));
      atomicAdd(&s_cnt[i0], 1);
      atomicAdd(&s_cnt[i1], 1);
    }
  }
  __syncthreads();
  if (tid < E_NUM) {
    atomicAdd(&probs_sum[tid], s_probs[tid]);
    atomicAdd(&counts[tid], s_cnt[tid]);
  }
  if (tid == E_NUM) atomicAdd(z_sum, s_z);
}

// ---------------- finalize: offsets + loss + 256-row tile list ----------------
__global__ void k_finalize(const int* __restrict__ counts, int* __restrict__ offsets,
                           const float* __restrict__ probs_sum, const float* __restrict__ z_sum,
                           float* __restrict__ loss_out,
                           int* __restrict__ n_tiles, int* __restrict__ tile_e,
                           int* __restrict__ tile_r0) {
  if (threadIdx.x == 0 && blockIdx.x == 0) {
    int off = 0; float aux = 0.f; int nt = 0;
    for (int e = 0; e < E_NUM; ++e) {
      offsets[e] = off; off += counts[e];
      aux += ((float)counts[e] / (float)(T_TOK * 2)) * (probs_sum[e] / (float)T_TOK);
      for (int r0 = 0; r0 < counts[e]; r0 += 256) {
        tile_e[nt] = e; tile_r0[nt] = r0; ++nt;
      }
    }
    *n_tiles = nt;
    *loss_out = (float)E_NUM * aux * 0.01f + 0.001f * (*z_sum / (float)T_TOK);
  }
}

// ---------------- scatter tokens to expert slots ----------------
__global__ __launch_bounds__(256) void k_scatter(
    const int* __restrict__ tok_e, const float* __restrict__ tok_w,
    const int* __restrict__ offsets, int* __restrict__ fill,
    int* __restrict__ rows, float* __restrict__ wgt, int* __restrict__ slot_of) {
  int t = blockIdx.x * 256 + threadIdx.x;
#pragma unroll
  for (int k = 0; k < 2; ++k) {
    int e = tok_e[t * 2 + k];
    int s = offsets[e] + atomicAdd(&fill[e], 1);
    rows[s] = t;
    wgt[s] = tok_w[t * 2 + k];
    slot_of[t * 2 + k] = s;
  }
}

// ---------------- GEMM1: 256x256x(K=2048) vs W2; SwiGLU epilogue -> h ----------------
// 512 thr = 8 waves (2M x 4N), per-wave 128x64; double-buffered 2-phase.
__global__ __launch_bounds__(512, 2) void k_gemm1(
    const unsigned short* __restrict__ xb, const unsigned short* __restrict__ w2b,
    const int* __restrict__ counts, const int* __restrict__ offsets,
    const int* __restrict__ rows, unsigned short* __restrict__ h,
    const int* __restrict__ n_tiles, const int* __restrict__ tile_e,
    const int* __restrict__ tile_r0) {
  int orig = blockIdx.x;
  int xcd = orig & 7, p = orig >> 3;   // p in [0, 288)
  int tile = p % NTS2, cl = p / NTS2;  // cl in [0,4)
  int ct = xcd * 4 + cl;               // [0, 32): 256-row W2 panel
  if (tile >= *n_tiles) return;
  int e = tile_e[tile], r0 = tile_r0[tile];
  int Te = counts[e], base = offsets[e];

  __shared__ __align__(16) unsigned short sA0[256 * 64], sA1[256 * 64];
  __shared__ __align__(16) unsigned short sB0[256 * 64], sB1[256 * 64];

  int tid = threadIdx.x, lane = tid & 63, wv = tid >> 6;
  int wr = wv >> 2, wc = wv & 3;
  int gsg = ((lane & 7) ^ (lane >> 3)) * 8;

  const unsigned short* a_src[4]; const unsigned short* b_src[4];
  int ldso[4];
#pragma unroll
  for (int i = 0; i < 4; ++i) {
    int r = i * 64 + wv * 8 + (lane >> 3);
    int lr = r0 + r; if (lr >= Te) lr = Te - 1;
    a_src[i] = xb + (size_t)rows[base + lr] * H + gsg;
    b_src[i] = w2b + ((size_t)e * (2 * I_DIM) + (size_t)ct * 256 + r) * H + gsg;
    ldso[i] = (i * 64 + wv * 8) * 64;
  }

  f32x4 acc[8][4];
#pragma unroll
  for (int m = 0; m < 8; ++m)
#pragma unroll
    for (int n = 0; n < 4; ++n) acc[m][n] = (f32x4)0.f;

#define STG(SA, SB, K0) do { \
  _Pragma("unroll") for (int i_ = 0; i_ < 4; ++i_) { \
    gload16(a_src[i_] + (K0), &SA[ldso[i_]]); \
    gload16(b_src[i_] + (K0), &SB[ldso[i_]]); } } while (0)

#define CMP1(SA, SB) do { \
  _Pragma("unroll") for (int kk = 0; kk < 2; ++kk) { \
    bf16x8 af[8], bf[4]; \
    _Pragma("unroll") for (int m = 0; m < 8; ++m) { \
      int r = wr * 128 + m * 16 + (lane & 15); \
      int g = (kk * 4 + (lane >> 4)) ^ (r & 7); \
      af[m] = *(const bf16x8*)&SA[r * 64 + g * 8]; } \
    _Pragma("unroll") for (int n = 0; n < 4; ++n) { \
      int r = wc * 64 + n * 16 + (lane & 15); \
      int g = (kk * 4 + (lane >> 4)) ^ (r & 7); \
      bf[n] = *(const bf16x8*)&SB[r * 64 + g * 8]; } \
    _Pragma("unroll") for (int m = 0; m < 8; ++m) \
      _Pragma("unroll") for (int n = 0; n < 4; ++n) \
        acc[m][n] = __builtin_amdgcn_mfma_f32_16x16x32_bf16(af[m], bf[n], acc[m][n], 0, 0, 0); \
  } } while (0)

  STG(sA0, sB0, 0);
  asm volatile("s_waitcnt vmcnt(0)" ::: "memory");
  __builtin_amdgcn_s_barrier();
#pragma unroll 1
  for (int t = 0; t < H / 64; t += 2) {
    STG(sA1, sB1, t * 64 + 64);
    CMP1(sA0, sB0);
    asm volatile("s_waitcnt vmcnt(0)" ::: "memory");
    __builtin_amdgcn_s_barrier();
    if (t + 2 < H / 64) STG(sA0, sB0, t * 64 + 128);
    CMP1(sA1, sB1);
    asm volatile("s_waitcnt vmcnt(0)" ::: "memory");
    __builtin_amdgcn_s_barrier();
  }

  // epilogue: n-pairs (even,odd) = (gate,up) for I-col group wc*2+np
  int hcb = ct * 128;
#pragma unroll
  for (int m = 0; m < 8; ++m)
#pragma unroll
    for (int j = 0; j < 4; ++j) {
      int lrow = wr * 128 + m * 16 + (lane >> 4) * 4 + j;
      if (r0 + lrow < Te) {
        unsigned short* hrow = h + (size_t)(base + r0 + lrow) * I_DIM + hcb + (lane & 15);
#pragma unroll
        for (int np = 0; np < 2; ++np) {
          float g = acc[m][2 * np][j], u = acc[m][2 * np + 1][j];
          float hv = g / (1.f + expf(-g)) * u;
          hrow[(wc * 2 + np) * 16] = f2bf(hv);
        }
      }
    }
}

// ---------------- GEMM2: 256x256x(K=4096) down -> weighted per-slot rows ----------------
__global__ __launch_bounds__(512, 2) void k_gemm2(
    const unsigned short* __restrict__ h, const unsigned short* __restrict__ dwb,
    const int* __restrict__ counts, const int* __restrict__ offsets,
    const float* __restrict__ wgt, float* __restrict__ dtmp,
    const int* __restrict__ n_tiles, const int* __restrict__ tile_e,
    const int* __restrict__ tile_r0) {
  int orig = blockIdx.x;
  int xcd = orig & 7, tile = orig >> 3;  // [0, 72)
  int ct = xcd;                          // H/256 = 8 panels, one per XCD
  if (tile >= *n_tiles) return;
  int e = tile_e[tile], r0 = tile_r0[tile];
  int Te = counts[e], base = offsets[e];

  __shared__ __align__(16) unsigned short sA0[256 * 64], sA1[256 * 64];
  __shared__ __align__(16) unsigned short sB0[256 * 64], sB1[256 * 64];

  int tid = threadIdx.x, lane = tid & 63, wv = tid >> 6;
  int wr = wv >> 2, wc = wv & 3;
  int gsg = ((lane & 7) ^ (lane >> 3)) * 8;

  const unsigned short* a_src[4]; const unsigned short* b_src[4];
  int ldso[4];
#pragma unroll
  for (int i = 0; i < 4; ++i) {
    int r = i * 64 + wv * 8 + (lane >> 3);
    int lr = r0 + r; if (lr >= Te) lr = Te - 1;
    a_src[i] = h + (size_t)(base + lr) * I_DIM + gsg;
    b_src[i] = dwb + ((size_t)e * H + (size_t)ct * 256 + r) * I_DIM + gsg;
    ldso[i] = (i * 64 + wv * 8) * 64;
  }

  f32x4 acc[8][4];
#pragma unroll
  for (int m = 0; m < 8; ++m)
#pragma unroll
    for (int n = 0; n < 4; ++n) acc[m][n] = (f32x4)0.f;

  STG(sA0, sB0, 0);
  asm volatile("s_waitcnt vmcnt(0)" ::: "memory");
  __builtin_amdgcn_s_barrier();
#pragma unroll 1
  for (int t = 0; t < I_DIM / 64; t += 2) {
    STG(sA1, sB1, t * 64 + 64);
    CMP1(sA0, sB0);
    asm volatile("s_waitcnt vmcnt(0)" ::: "memory");
    __builtin_amdgcn_s_barrier();
    if (t + 2 < I_DIM / 64) STG(sA0, sB0, t * 64 + 128);
    CMP1(sA1, sB1);
    asm volatile("s_waitcnt vmcnt(0)" ::: "memory");
    __builtin_amdgcn_s_barrier();
  }

  int cbase = ct * 256 + wc * 64;
#pragma unroll
  for (int m = 0; m < 8; ++m)
#pragma unroll
    for (int j = 0; j < 4; ++j) {
      int lrow = wr * 128 + m * 16 + (lane >> 4) * 4 + j;
      if (r0 + lrow < Te) {
        int slot = base + r0 + lrow;
        float w = wgt[slot];
        float* drow = dtmp + (size_t)slot * H + cbase + (lane & 15);
#pragma unroll
        for (int n = 0; n < 4; ++n)
          drow[n * 16] = acc[m][n][j] * w;
      }
    }
}

// ---------------- combine: out[t] = dtmp[slot0] + dtmp[slot1] ----------------
__global__ __launch_bounds__(256) void k_combine(const float* __restrict__ dtmp,
                                                 const int* __restrict__ slot_of,
                                                 float* __restrict__ out) {
  int t = blockIdx.x >> 1;
  int c = ((blockIdx.x & 1) * 256 + threadIdx.x) * 4;
  int s0 = slot_of[t * 2], s1 = slot_of[t * 2 + 1];
  f32x4 a = *(const f32x4*)(dtmp + (size_t)s0 * H + c);
  f32x4 b = *(const f32x4*)(dtmp + (size_t)s1 * H + c);
  *(f32x4*)(out + (size_t)t * H + c) = a + b;
}

extern "C" void kernel_launch(void* const* d_in, const int* in_sizes, int n_in,
                              void* d_out, int out_size, void* d_ws, size_t ws_size,
                              hipStream_t stream) {
  const float* x  = (const float*)d_in[0];
  const float* rw = (const float*)d_in[1];
  const float* gw = (const float*)d_in[2];
  const float* uw = (const float*)d_in[3];
  const float* dw = (const float*)d_in[4];
  float* out = (float*)d_out;

  char* ws = (char*)d_ws;
  int*   counts    = (int*)(ws + 0);      // 8
  int*   fill      = (int*)(ws + 32);     // 8
  int*   offsets   = (int*)(ws + 64);     // 8
  float* probs_sum = (float*)(ws + 96);   // 8
  float* z_sum     = (float*)(ws + 128);  // 1
  int*   n_tiles   = (int*)(ws + 132);    // 1
  int*   tile_e    = (int*)(ws + 256);
  int*   tile_r0   = (int*)(ws + 2304);
  int*   tok_e     = (int*)(ws + 8192);
  float* tok_w     = (float*)(ws + 8192 + 65536);
  int*   rows      = (int*)(ws + 8192 + 131072);
  float* wgt       = (float*)(ws + 8192 + 196608);
  int*   slot_of   = (int*)(ws + 8192 + 262144);
  size_t off = 8192 + 327680;
  unsigned short* xb  = (unsigned short*)(ws + off); off += (size_t)T_TOK * H * 2;
  unsigned short* hb  = (unsigned short*)(ws + off); off += (size_t)SLOTS * I_DIM * 2;
  unsigned short* w2b = (unsigned short*)(ws + off); off += (size_t)E_NUM * 2 * I_DIM * H * 2;
  unsigned short* dwb = (unsigned short*)(ws + off); off += (size_t)E_NUM * H * I_DIM * 2;
  float* dtmp = (float*)w2b;  // w2b dead after gemm1; SLOTS*H*4 <= E*2I*H*2

  hipMemsetAsync(ws, 0, 256, stream);

  const size_t WN = (size_t)E_NUM * I_DIM * H;  // 67.1M elements per weight tensor
  k_cvt<<<(T_TOK * H / 8) / 256, 256, 0, stream>>>(x, xb);
  k_cvt_w<<<(3 * WN / 8) / 256, 256, 0, stream>>>(gw, uw, dw, w2b, dwb);
  k_router<<<T_TOK / 32, 256, 0, stream>>>(x, rw, tok_e, tok_w, counts, probs_sum, z_sum);
  k_finalize<<<1, 64, 0, stream>>>(counts, offsets, probs_sum, z_sum, out + (out_size - 1),
                                   n_tiles, tile_e, tile_r0);
  k_scatter<<<T_TOK / 256, 256, 0, stream>>>(tok_e, tok_w, offsets, fill, rows, wgt, slot_of);
  k_gemm1<<<NTS2 * 32, 512, 0, stream>>>(xb, w2b, counts, offsets, rows, hb,
                                         n_tiles, tile_e, tile_r0);
  k_gemm2<<<NTS2 * 8, 512, 0, stream>>>(hb, dwb, counts, offsets, wgt, dtmp,
                                        n_tiles, tile_e, tile_r0);
  k_combine<<<T_TOK * 2, 256, 0, stream>>>(dtmp, slot_of, out);
}

// Round 10
// 1288.865 us; speedup vs baseline: 1.2200x; 1.2200x over previous
//
#include <hip/hip_runtime.h>

#define H 2048
#define I_DIM 4096
#define E_NUM 8
#define T_TOK 8192
#define SLOTS 16384
#define NTS 136   // max active row-tiles: sum_e ceil(Te/128) <= 128 + 7 = 135 (pad to 136 = 34*4)

typedef __attribute__((ext_vector_type(8))) short bf16x8;
typedef __attribute__((ext_vector_type(4))) float f32x4;
typedef __attribute__((ext_vector_type(8))) unsigned short u16x8;

__device__ __forceinline__ unsigned short f2bf(float f) {
  union { float f; unsigned int u; } v; v.f = f;
  unsigned int r = v.u + 0x7fffu + ((v.u >> 16) & 1u);
  return (unsigned short)(r >> 16);
}

__device__ __forceinline__ float bf2f(unsigned short u) {
  union { unsigned int i; float f; } v; v.i = (unsigned int)u << 16; return v.f;
}

// async global->LDS, 16B per lane; LDS dest is wave-uniform base + lane*16
__device__ __forceinline__ void gload16(const unsigned short* g, unsigned short* l) {
  __builtin_amdgcn_global_load_lds(
      (const __attribute__((address_space(1))) unsigned int*)g,
      (__attribute__((address_space(3))) unsigned int*)l, 16, 0, 0);
}

// ---------------- x convert (f32 -> bf16) ----------------
__global__ __launch_bounds__(256) void k_cvt(const float* __restrict__ x,
                                             unsigned short* __restrict__ xb) {
  size_t i = ((size_t)blockIdx.x * 256 + threadIdx.x) * 8;
  f32x4 a = *(const f32x4*)(x + i);
  f32x4 b = *(const f32x4*)(x + i + 4);
  u16x8 o;
#pragma unroll
  for (int j = 0; j < 4; ++j) { o[j] = f2bf(a[j]); o[4 + j] = f2bf(b[j]); }
  *(u16x8*)(xb + i) = o;
}

// ---------------- all three weight tensors in one launch ----------------
__global__ __launch_bounds__(256) void k_cvt_w(
    const float* __restrict__ gw, const float* __restrict__ uw, const float* __restrict__ dw,
    unsigned short* __restrict__ gwb, unsigned short* __restrict__ uwb,
    unsigned short* __restrict__ dwb) {
  const size_t per = (size_t)E_NUM * I_DIM * H / 8;  // granules per tensor
  size_t gid = (size_t)blockIdx.x * 256 + threadIdx.x;
  const float* s; unsigned short* d; size_t idx;
  if (gid < per)            { s = gw; d = gwb; idx = gid; }
  else if (gid < 2 * per)   { s = uw; d = uwb; idx = gid - per; }
  else                      { s = dw; d = dwb; idx = gid - 2 * per; }
  size_t i = idx * 8;
  f32x4 a = *(const f32x4*)(s + i);
  f32x4 b = *(const f32x4*)(s + i + 4);
  u16x8 o;
#pragma unroll
  for (int j = 0; j < 4; ++j) { o[j] = f2bf(a[j]); o[4 + j] = f2bf(b[j]); }
  *(u16x8*)(d + i) = o;
}

// ---------------- router ----------------
__global__ __launch_bounds__(256) void k_router(
    const float* __restrict__ x, const float* __restrict__ rw,
    int* __restrict__ tok_e, float* __restrict__ tok_w,
    int* __restrict__ counts, float* __restrict__ probs_sum, float* __restrict__ z_sum) {
  __shared__ __align__(16) float s_rw[E_NUM * H];
  __shared__ float s_probs[E_NUM];
  __shared__ float s_z;
  __shared__ int s_cnt[E_NUM];
  int tid = threadIdx.x;
  if (tid < E_NUM) { s_probs[tid] = 0.f; s_cnt[tid] = 0; }
  if (tid == 0) s_z = 0.f;
  for (int i = tid * 4; i < E_NUM * H; i += 256 * 4)
    *(f32x4*)&s_rw[i] = *(const f32x4*)&rw[i];
  __syncthreads();

  int lane = tid & 63, wv = tid >> 6;

  for (int it = 0; it < 8; ++it) {
    int t = blockIdx.x * 32 + wv * 8 + it;
    const float* xr = x + (size_t)t * H;

    float acc[E_NUM];
#pragma unroll
    for (int e = 0; e < E_NUM; ++e) acc[e] = 0.f;
    for (int j = 0; j < H / 64; ++j) {
      int c = j * 64 + lane;
      float xv = xr[c];
#pragma unroll
      for (int e = 0; e < E_NUM; ++e) acc[e] = fmaf(xv, s_rw[e * H + c], acc[e]);
    }
#pragma unroll
    for (int e = 0; e < E_NUM; ++e) {
      float v = acc[e];
#pragma unroll
      for (int off = 32; off > 0; off >>= 1) v += __shfl_down(v, off, 64);
      acc[e] = v;
    }
    if (lane == 0) {
      int i0 = 0; float l0 = acc[0];
#pragma unroll
      for (int e = 1; e < E_NUM; ++e) if (acc[e] > l0) { l0 = acc[e]; i0 = e; }
      int i1 = -1; float l1 = -3.4e38f;
#pragma unroll
      for (int e = 0; e < E_NUM; ++e) if (e != i0 && acc[e] > l1) { l1 = acc[e]; i1 = e; }
      float w0 = 1.f / (1.f + expf(l1 - l0));
      tok_e[t * 2] = i0; tok_e[t * 2 + 1] = i1;
      tok_w[t * 2] = w0; tok_w[t * 2 + 1] = 1.f - w0;

      float s = 0.f; float p[E_NUM];
#pragma unroll
      for (int e = 0; e < E_NUM; ++e) { p[e] = expf(acc[e] - l0); s += p[e]; }
      float inv = 1.f / s;
#pragma unroll
      for (int e = 0; e < E_NUM; ++e) atomicAdd(&s_probs[e], p[e] * inv);
      atomicAdd(&s_z, l0 + logf(s));
      atomicAdd(&s_cnt[i0], 1);
      atomicAdd(&s_cnt[i1], 1);
    }
  }
  __syncthreads();
  if (tid < E_NUM) {
    atomicAdd(&probs_sum[tid], s_probs[tid]);
    atomicAdd(&counts[tid], s_cnt[tid]);
  }
  if (tid == E_NUM) atomicAdd(z_sum, s_z);
}

// ---------------- finalize: offsets + loss + active tile list ----------------
__global__ void k_finalize(const int* __restrict__ counts, int* __restrict__ offsets,
                           const float* __restrict__ probs_sum, const float* __restrict__ z_sum,
                           float* __restrict__ loss_out,
                           int* __restrict__ n_tiles, int* __restrict__ tile_e,
                           int* __restrict__ tile_r0) {
  if (threadIdx.x == 0 && blockIdx.x == 0) {
    int off = 0; float aux = 0.f; int nt = 0;
    for (int e = 0; e < E_NUM; ++e) {
      offsets[e] = off; off += counts[e];
      aux += ((float)counts[e] / (float)(T_TOK * 2)) * (probs_sum[e] / (float)T_TOK);
      for (int r0 = 0; r0 < counts[e]; r0 += 128) {
        tile_e[nt] = e; tile_r0[nt] = r0; ++nt;
      }
    }
    *n_tiles = nt;
    *loss_out = (float)E_NUM * aux * 0.01f + 0.001f * (*z_sum / (float)T_TOK);
  }
}

// ---------------- scatter tokens to expert slots ----------------
__global__ __launch_bounds__(256) void k_scatter(
    const int* __restrict__ tok_e, const float* __restrict__ tok_w,
    const int* __restrict__ offsets, int* __restrict__ fill,
    int* __restrict__ rows, float* __restrict__ wgt, int* __restrict__ slot_of) {
  int t = blockIdx.x * 256 + threadIdx.x;
#pragma unroll
  for (int k = 0; k < 2; ++k) {
    int e = tok_e[t * 2 + k];
    int s = offsets[e] + atomicAdd(&fill[e], 1);
    rows[s] = t;
    wgt[s] = tok_w[t * 2 + k];
    slot_of[t * 2 + k] = s;
  }
}

// ---------------- GEMM1: gate+up + SwiGLU -> h (bf16) ----------------
// grid = NTS x 64. XCD-chunked; within each XCD chunk: groups of 4 tiles x 8 cts,
// ct fastest -> each A-tile fetched from HBM once (L2-resident across its 8 cts),
// weight panels (8MB/group) LLC-served and reused across the 4 tiles. (R7-proven.)
__global__ __launch_bounds__(256, 2) void k_gemm1(
    const unsigned short* __restrict__ xb,
    const unsigned short* __restrict__ gwb, const unsigned short* __restrict__ uwb,
    const int* __restrict__ counts, const int* __restrict__ offsets,
    const int* __restrict__ rows, unsigned short* __restrict__ h,
    const int* __restrict__ n_tiles, const int* __restrict__ tile_e,
    const int* __restrict__ tile_r0) {
  int orig = blockIdx.y * NTS + blockIdx.x;
  int xcd = orig & 7;
  int p = orig >> 3;            // position within this XCD's chunk [0, 1088)
  int grp = p >> 5;             // 34 groups of (4 tiles x 8 cts)
  int q = p & 31;
  int bxt = grp * 4 + (q >> 3); // tile index [0, 136)
  int ct = xcd * 8 + (q & 7);   // ct in [0, 64); XCD owns 8 consecutive cts
  if (bxt >= *n_tiles) return;
  int e = tile_e[bxt];
  int r0 = tile_r0[bxt];
  int Te = counts[e];
  int base = offsets[e];

  __shared__ __align__(16) unsigned short sA[128 * 64];
  __shared__ __align__(16) unsigned short sG[64 * 64];
  __shared__ __align__(16) unsigned short sU[64 * 64];

  int tid = threadIdx.x, lane = tid & 63, wv = tid >> 6;
  int wr = wv >> 1, wc = wv & 1;

  // pre-swizzled global granule so linear LDS write == swizzled content
  int gsg = ((lane & 7) ^ (lane >> 3)) * 8;

  const unsigned short* a_src[4];
  unsigned short* a_dst[4];
#pragma unroll
  for (int i = 0; i < 4; ++i) {
    int r = 32 * wv + 8 * i + (lane >> 3);
    int lr = r0 + r; if (lr >= Te) lr = Te - 1;
    a_src[i] = xb + (size_t)rows[base + lr] * H + gsg;
    a_dst[i] = sA + (32 * wv + 8 * i) * 64;
  }
  const unsigned short* g_src[2]; const unsigned short* u_src[2];
  unsigned short* g_dst[2]; unsigned short* u_dst[2];
#pragma unroll
  for (int j = 0; j < 2; ++j) {
    int r = 16 * wv + 8 * j + (lane >> 3);
    size_t wrow = ((size_t)e * I_DIM + (size_t)ct * 64 + r) * H + gsg;
    g_src[j] = gwb + wrow;
    u_src[j] = uwb + wrow;
    g_dst[j] = sG + (16 * wv + 8 * j) * 64;
    u_dst[j] = sU + (16 * wv + 8 * j) * 64;
  }

  f32x4 accg[4][2], accu[4][2];
#pragma unroll
  for (int m = 0; m < 4; ++m)
#pragma unroll
    for (int n = 0; n < 2; ++n) { accg[m][n] = (f32x4)0.f; accu[m][n] = (f32x4)0.f; }

  for (int k0 = 0; k0 < H; k0 += 64) {
#pragma unroll
    for (int i = 0; i < 4; ++i) gload16(a_src[i] + k0, a_dst[i]);
#pragma unroll
    for (int j = 0; j < 2; ++j) gload16(g_src[j] + k0, g_dst[j]);
#pragma unroll
    for (int j = 0; j < 2; ++j) gload16(u_src[j] + k0, u_dst[j]);
    __syncthreads();

#pragma unroll
    for (int kk = 0; kk < 2; ++kk) {
      bf16x8 af[4], gf[2], uf[2];
#pragma unroll
      for (int m = 0; m < 4; ++m) {
        int r = 64 * wr + m * 16 + (lane & 15);
        int g = (kk * 4 + (lane >> 4)) ^ (r & 7);
        af[m] = *(const bf16x8*)&sA[r * 64 + g * 8];
      }
#pragma unroll
      for (int n = 0; n < 2; ++n) {
        int r = 32 * wc + n * 16 + (lane & 15);
        int g = (kk * 4 + (lane >> 4)) ^ (r & 7);
        gf[n] = *(const bf16x8*)&sG[r * 64 + g * 8];
        uf[n] = *(const bf16x8*)&sU[r * 64 + g * 8];
      }
#pragma unroll
      for (int m = 0; m < 4; ++m)
#pragma unroll
        for (int n = 0; n < 2; ++n) {
          accg[m][n] = __builtin_amdgcn_mfma_f32_16x16x32_bf16(af[m], gf[n], accg[m][n], 0, 0, 0);
          accu[m][n] = __builtin_amdgcn_mfma_f32_16x16x32_bf16(af[m], uf[n], accu[m][n], 0, 0, 0);
        }
    }
    __syncthreads();
  }

  int cbase = ct * 64 + wc * 32;
#pragma unroll
  for (int m = 0; m < 4; ++m)
#pragma unroll
    for (int j = 0; j < 4; ++j) {
      int lrow = 64 * wr + m * 16 + (lane >> 4) * 4 + j;
      if (r0 + lrow < Te) {
        unsigned short* hrow = h + (size_t)(base + r0 + lrow) * I_DIM + cbase + (lane & 15);
#pragma unroll
        for (int n = 0; n < 2; ++n) {
          float g = accg[m][n][j], u = accu[m][n][j];
          float hv = g / (1.f + expf(-g)) * u;
          hrow[n * 16] = f2bf(hv);
        }
      }
    }
}

// ---------------- GEMM2: down -> weighted per-slot rows (bf16, no atomics) ----------------
// grid = NTS x 16; groups of 4 tiles x 2 cts per XCD chunk, ct fastest. (R7-proven.)
__global__ __launch_bounds__(256, 2) void k_gemm2(
    const unsigned short* __restrict__ h, const unsigned short* __restrict__ dwb,
    const int* __restrict__ counts, const int* __restrict__ offsets,
    const float* __restrict__ wgt, unsigned short* __restrict__ dtmp,
    const int* __restrict__ n_tiles, const int* __restrict__ tile_e,
    const int* __restrict__ tile_r0) {
  int orig = blockIdx.y * NTS + blockIdx.x;
  int xcd = orig & 7;
  int p = orig >> 3;            // [0, 272)
  int grp = p >> 3;             // 34 groups of (4 tiles x 2 cts)
  int q = p & 7;
  int bxt = grp * 4 + (q >> 1);
  int ct = xcd * 2 + (q & 1);   // ct in [0, 16)
  if (bxt >= *n_tiles) return;
  int e = tile_e[bxt];
  int r0 = tile_r0[bxt];
  int Te = counts[e];
  int base = offsets[e];

  __shared__ __align__(16) unsigned short sA[128 * 64];
  __shared__ __align__(16) unsigned short sB[128 * 64];

  int tid = threadIdx.x, lane = tid & 63, wv = tid >> 6;
  int wr = wv >> 1, wc = wv & 1;

  int gsg = ((lane & 7) ^ (lane >> 3)) * 8;

  const unsigned short* a_src[4];
  unsigned short* a_dst[4];
#pragma unroll
  for (int i = 0; i < 4; ++i) {
    int r = 32 * wv + 8 * i + (lane >> 3);
    int lr = r0 + r; if (lr >= Te) lr = Te - 1;
    a_src[i] = h + (size_t)(base + lr) * I_DIM + gsg;
    a_dst[i] = sA + (32 * wv + 8 * i) * 64;
  }
  const unsigned short* b_src[4];
  unsigned short* b_dst[4];
#pragma unroll
  for (int i = 0; i < 4; ++i) {
    int r = 32 * wv + 8 * i + (lane >> 3);
    b_src[i] = dwb + ((size_t)e * H + (size_t)ct * 128 + r) * I_DIM + gsg;
    b_dst[i] = sB + (32 * wv + 8 * i) * 64;
  }

  f32x4 acc[4][4];
#pragma unroll
  for (int m = 0; m < 4; ++m)
#pragma unroll
    for (int n = 0; n < 4; ++n) acc[m][n] = (f32x4)0.f;

  for (int k0 = 0; k0 < I_DIM; k0 += 64) {
#pragma unroll
    for (int i = 0; i < 4; ++i) gload16(a_src[i] + k0, a_dst[i]);
#pragma unroll
    for (int i = 0; i < 4; ++i) gload16(b_src[i] + k0, b_dst[i]);
    __syncthreads();

#pragma unroll
    for (int kk = 0; kk < 2; ++kk) {
      bf16x8 af[4], bf[4];
#pragma unroll
      for (int m = 0; m < 4; ++m) {
        int r = 64 * wr + m * 16 + (lane & 15);
        int g = (kk * 4 + (lane >> 4)) ^ (r & 7);
        af[m] = *(const bf16x8*)&sA[r * 64 + g * 8];
      }
#pragma unroll
      for (int n = 0; n < 4; ++n) {
        int r = 64 * wc + n * 16 + (lane & 15);
        int g = (kk * 4 + (lane >> 4)) ^ (r & 7);
        bf[n] = *(const bf16x8*)&sB[r * 64 + g * 8];
      }
#pragma unroll
      for (int m = 0; m < 4; ++m)
#pragma unroll
        for (int n = 0; n < 4; ++n)
          acc[m][n] = __builtin_amdgcn_mfma_f32_16x16x32_bf16(af[m], bf[n], acc[m][n], 0, 0, 0);
    }
    __syncthreads();
  }

  int cbase = ct * 128 + wc * 64;
#pragma unroll
  for (int m = 0; m < 4; ++m)
#pragma unroll
    for (int j = 0; j < 4; ++j) {
      int lrow = 64 * wr + m * 16 + (lane >> 4) * 4 + j;
      if (r0 + lrow < Te) {
        int slot = base + r0 + lrow;
        float w = wgt[slot];
        unsigned short* drow = dtmp + (size_t)slot * H + cbase + (lane & 15);
#pragma unroll
        for (int n = 0; n < 4; ++n)
          drow[n * 16] = f2bf(acc[m][n][j] * w);
      }
    }
}

// ---------------- combine: out[t] = dtmp[slot0] + dtmp[slot1] (bf16 -> f32) ----------------
__global__ __launch_bounds__(256) void k_combine(const unsigned short* __restrict__ dtmp,
                                                 const int* __restrict__ slot_of,
                                                 float* __restrict__ out) {
  int t = blockIdx.x;
  int c = threadIdx.x * 8;
  int s0 = slot_of[t * 2], s1 = slot_of[t * 2 + 1];
  u16x8 a = *(const u16x8*)(dtmp + (size_t)s0 * H + c);
  u16x8 b = *(const u16x8*)(dtmp + (size_t)s1 * H + c);
  f32x4 o0, o1;
#pragma unroll
  for (int j = 0; j < 4; ++j) {
    o0[j] = bf2f(a[j]) + bf2f(b[j]);
    o1[j] = bf2f(a[4 + j]) + bf2f(b[4 + j]);
  }
  *(f32x4*)(out + (size_t)t * H + c) = o0;
  *(f32x4*)(out + (size_t)t * H + c + 4) = o1;
}

extern "C" void kernel_launch(void* const* d_in, const int* in_sizes, int n_in,
                              void* d_out, int out_size, void* d_ws, size_t ws_size,
                              hipStream_t stream) {
  const float* x  = (const float*)d_in[0];
  const float* rw = (const float*)d_in[1];
  const float* gw = (const float*)d_in[2];
  const float* uw = (const float*)d_in[3];
  const float* dw = (const float*)d_in[4];
  float* out = (float*)d_out;

  char* ws = (char*)d_ws;
  int*   counts    = (int*)(ws + 0);      // 8
  int*   fill      = (int*)(ws + 32);     // 8
  int*   offsets   = (int*)(ws + 64);     // 8
  float* probs_sum = (float*)(ws + 96);   // 8
  float* z_sum     = (float*)(ws + 128);  // 1
  int*   n_tiles   = (int*)(ws + 132);    // 1
  int*   tile_e    = (int*)(ws + 256);
  int*   tile_r0   = (int*)(ws + 2304);
  int*   tok_e     = (int*)(ws + 8192);
  float* tok_w     = (float*)(ws + 8192 + 65536);
  int*   rows      = (int*)(ws + 8192 + 131072);
  float* wgt       = (float*)(ws + 8192 + 196608);
  int*   slot_of   = (int*)(ws + 8192 + 262144);
  size_t off = 8192 + 327680;
  unsigned short* xb  = (unsigned short*)(ws + off); off += (size_t)T_TOK * H * 2;
  unsigned short* hb  = (unsigned short*)(ws + off); off += (size_t)SLOTS * I_DIM * 2;
  unsigned short* gwb = (unsigned short*)(ws + off); off += (size_t)E_NUM * I_DIM * H * 2;
  unsigned short* uwb = (unsigned short*)(ws + off); off += (size_t)E_NUM * I_DIM * H * 2;
  unsigned short* dwb = (unsigned short*)(ws + off); off += (size_t)E_NUM * H * I_DIM * 2;
  unsigned short* dtmp = (unsigned short*)gwb;  // gwb dead after gemm1; SLOTS*H*2 << E*I*H*2

  hipMemsetAsync(ws, 0, 256, stream);

  const size_t WN = (size_t)E_NUM * I_DIM * H;  // 67.1M elements per weight tensor
  k_cvt<<<(T_TOK * H / 8) / 256, 256, 0, stream>>>(x, xb);
  k_cvt_w<<<(3 * WN / 8) / 256, 256, 0, stream>>>(gw, uw, dw, gwb, uwb, dwb);
  k_router<<<T_TOK / 32, 256, 0, stream>>>(x, rw, tok_e, tok_w, counts, probs_sum, z_sum);
  k_finalize<<<1, 64, 0, stream>>>(counts, offsets, probs_sum, z_sum, out + (out_size - 1),
                                   n_tiles, tile_e, tile_r0);
  k_scatter<<<T_TOK / 256, 256, 0, stream>>>(tok_e, tok_w, offsets, fill, rows, wgt, slot_of);
  k_gemm1<<<dim3(NTS, I_DIM / 64), 256, 0, stream>>>(xb, gwb, uwb, counts, offsets, rows, hb,
                                                     n_tiles, tile_e, tile_r0);
  k_gemm2<<<dim3(NTS, H / 128), 256, 0, stream>>>(hb, dwb, counts, offsets, wgt, dtmp,
                                                  n_tiles, tile_e, tile_r0);
  k_combine<<<T_TOK, 256, 0, stream>>>(dtmp, slot_of, out);
}